// Round 5
// baseline (121.180 us; speedup 1.0000x reference)
//
#include <hip/hip_runtime.h>
#include <hip/hip_bf16.h>

#define C 128
#define HW 4096
#define NPOS 65536
#define K 1024
#define MB 128           // positions per block
#define NBLK (NPOS/MB)   // 512
#define RS 136           // zt padded row stride in bf16 elems (272 B)
#define RSB 320          // codebook image row stride BYTES (64B-aligned segments)
#define CHK 64           // codes per chunk
#define NCH (K/CHK)      // 16
#define CHB (CHK*RSB)    // 20480 bytes per chunk

#define ZQ_OFF 0
#define LOSS_OFF 8388608
#define IDX_OFF 8388609
#define COMMIT_OFF 8454145
#define CODE_OFF 8454146

#define WS_IMG_OFF 8192  // bf16 codebook image at d_ws + 8192, 1024*320 B

typedef __bf16 bf16x8 __attribute__((ext_vector_type(8)));
typedef float f32x4 __attribute__((ext_vector_type(4)));

// Padded bf16 codebook image: row k = 128 bf16 at 320B stride (each 64B
// quarter-row cache-line aligned), fp32 (||e_k||^2 + 1.0) at row+256.
// Block 0 zeroes the loss accumulator (replaces the memset dispatch).
__global__ void vq_prep(const float* __restrict__ emb, unsigned char* __restrict__ img,
                        float* __restrict__ S) {
    int k = blockIdx.x;
    int l = threadIdx.x;            // 64 threads
    if (k == 0 && l == 0) S[0] = 0.0f;
    float v0 = emb[k * C + l];
    float v1 = emb[k * C + 64 + l];
    __hip_bfloat16 h0 = __float2bfloat16(v0);
    __hip_bfloat16 h1 = __float2bfloat16(v1);
    unsigned short* row = (unsigned short*)(img + (size_t)k * RSB);
    row[l] = *(unsigned short*)&h0;
    row[64 + l] = *(unsigned short*)&h1;
    float s = v0 * v0 + v1 * v1;
    #pragma unroll
    for (int off = 32; off; off >>= 1) s += __shfl_down(s, off);
    if (l == 0) *(float*)(img + (size_t)k * RSB + 256) = s + 1.0f;
}

// 512 threads (8 waves, 2M x 4N), grid 512 -> 2 blocks/CU = 16 waves/CU =
// 4 waves/SIMD (2x the old occupancy). Codebook LDS staging deleted: each
// wave reads its 16 B-rows per chunk straight global->VGPR (L2-resident
// image), so the chunk loop has ZERO barriers and waves slip freely -- TLP
// hides the load latency that the old per-chunk vmcnt(0)+barrier exposed.
__global__ __launch_bounds__(512, 4)
void vq_main(const float* __restrict__ z, const float* __restrict__ emb,
             const unsigned char* __restrict__ img,
             float* __restrict__ out, float* __restrict__ S) {
    __shared__ __align__(16) unsigned short zt[MB * RS];  // 34816 B
    __shared__ unsigned int wbest[4][MB];                 // 2048 B (indexed by wn)
    __shared__ unsigned short idxs[MB];                   // 256 B
    __shared__ float lred[8];
    // total ~37 KB -> thread-capped at 2 blocks/CU, not LDS-capped

    const int t = threadIdx.x;
    const int w = t >> 6;
    const int lane = t & 63;
    const int nn = lane & 15;      // MFMA: A row m / B col n / C col
    const int q = lane >> 4;       // quad
    const int wm = w >> 2;         // M-half: positions wm*64..+63
    const int wn = w & 3;          // N-quarter: codes wn*16..+15 of each chunk

    const int blk = blockIdx.x;
    const int n0g = blk * MB;
    const int b = n0g >> 12;
    const int hw0 = n0g & (HW - 1);
    const float* zg = z + (size_t)b * C * HW + hw0;

    // stage z tile -> LDS bf16 [pos][c], row stride 272B (512 thr: 32 ch each)
    {
        int pos = t & (MB - 1);
        int c0b = (t >> 7) * 32;
        #pragma unroll
        for (int i = 0; i < 8; ++i) {
            int c0 = c0b + i * 4;
            float f0 = zg[(size_t)(c0 + 0) * HW + pos];
            float f1 = zg[(size_t)(c0 + 1) * HW + pos];
            float f2 = zg[(size_t)(c0 + 2) * HW + pos];
            float f3 = zg[(size_t)(c0 + 3) * HW + pos];
            __hip_bfloat16 h0 = __float2bfloat16(f0), h1 = __float2bfloat16(f1),
                           h2 = __float2bfloat16(f2), h3 = __float2bfloat16(f3);
            ushort4 pk;
            pk.x = *(unsigned short*)&h0; pk.y = *(unsigned short*)&h1;
            pk.z = *(unsigned short*)&h2; pk.w = *(unsigned short*)&h3;
            *(ushort4*)&zt[pos * RS + c0] = pk;
        }
    }
    __syncthreads();   // the ONLY pre-reduction barrier

    // A fragments: 4 M-tiles x 4 K-steps = 64 VGPRs, resident across chunks
    bf16x8 a[4][4];
    #pragma unroll
    for (int mt = 0; mt < 4; ++mt)
        #pragma unroll
        for (int ks = 0; ks < 4; ++ks)
            a[mt][ks] = *(bf16x8*)&zt[(wm * 64 + mt * 16 + nn) * RS + ks * 32 + q * 8];

    unsigned int best[4][4];
    #pragma unroll
    for (int mt = 0; mt < 4; ++mt)
        #pragma unroll
        for (int r = 0; r < 4; ++r) best[mt][r] = 0xFFFFFFFFu;

    // per-lane B pointers: lane (nn,q) reads quarter-row q of code wn*16+nn
    const unsigned char* pb = img + (size_t)(wn * 16 + nn) * RSB + q * 16;
    const unsigned char* pe = img + (size_t)(wn * 16 + nn) * RSB + 256;

    for (int ch = 0; ch < NCH; ++ch) {
        bf16x8 bf[4];
        #pragma unroll
        for (int ks = 0; ks < 4; ++ks)
            bf[ks] = *(const bf16x8*)(pb + ks * 64);
        const float en1 = *(const float*)pe;
        const unsigned int code = (unsigned int)(ch * CHK + wn * 16 + nn);

        f32x4 acc[4];
        #pragma unroll
        for (int mt = 0; mt < 4; ++mt) acc[mt] = (f32x4){0.f, 0.f, 0.f, 0.f};
        #pragma unroll
        for (int ks = 0; ks < 4; ++ks)
            #pragma unroll
            for (int mt = 0; mt < 4; ++mt)
                acc[mt] = __builtin_amdgcn_mfma_f32_16x16x32_bf16(a[mt][ks], bf[ks], acc[mt], 0, 0, 0);

        // packed argmin: score' = (enorm+1) - 2*dot (always ~1.0 > 0),
        // clear low 10 mantissa bits, OR in code; u32 min == float min + tie-low.
        #pragma unroll
        for (int mt = 0; mt < 4; ++mt)
            #pragma unroll
            for (int r = 0; r < 4; ++r) {
                float s = fmaf(acc[mt][r], -2.0f, en1);
                unsigned int u = (__float_as_uint(s) & ~1023u) | code;
                best[mt][r] = min(best[mt][r], u);
            }
        pb += CHB; pe += CHB;
    }

    // in-wave reduce over the 16 code-columns (xor lanes 1,2,4,8 stay in quad)
    #pragma unroll
    for (int mt = 0; mt < 4; ++mt)
        #pragma unroll
        for (int r = 0; r < 4; ++r) {
            unsigned int v = best[mt][r];
            v = min(v, (unsigned int)__shfl_xor((int)v, 1));
            v = min(v, (unsigned int)__shfl_xor((int)v, 2));
            v = min(v, (unsigned int)__shfl_xor((int)v, 4));
            v = min(v, (unsigned int)__shfl_xor((int)v, 8));
            if (nn == 0) wbest[wn][wm * 64 + mt * 16 + q * 4 + r] = v;
        }
    __syncthreads();

    if (t < MB) {
        unsigned int v = min(min(wbest[0][t], wbest[1][t]), min(wbest[2][t], wbest[3][t]));
        unsigned int code = v & 1023u;
        idxs[t] = (unsigned short)code;
        out[IDX_OFF + n0g + t] = (float)code;
    }
    __syncthreads();

    // epilogue: exact fp32 gather of chosen code rows, z_q store, loss
    {
        int pos = t & (MB - 1);
        int c0b = (t >> 7) * 32;
        int myidx = idxs[pos];
        const float* erow = emb + (size_t)myidx * C;
        float* og = out + ZQ_OFF + (size_t)b * C * HW + hw0;
        float ls = 0.f;
        #pragma unroll
        for (int i = 0; i < 8; ++i) {
            int c0 = c0b + i * 4;
            float4 ev = *(const float4*)&erow[c0];
            ushort4 zz = *(ushort4*)&zt[pos * RS + c0];
            float z0 = __uint_as_float((unsigned int)zz.x << 16);
            float z1 = __uint_as_float((unsigned int)zz.y << 16);
            float z2 = __uint_as_float((unsigned int)zz.z << 16);
            float z3 = __uint_as_float((unsigned int)zz.w << 16);
            float d0 = z0 - ev.x, d1 = z1 - ev.y, d2 = z2 - ev.z, d3 = z3 - ev.w;
            ls += d0 * d0 + d1 * d1 + d2 * d2 + d3 * d3;
            og[(size_t)(c0 + 0) * HW + pos] = ev.x;
            og[(size_t)(c0 + 1) * HW + pos] = ev.y;
            og[(size_t)(c0 + 2) * HW + pos] = ev.z;
            og[(size_t)(c0 + 3) * HW + pos] = ev.w;
        }
        #pragma unroll
        for (int off = 32; off; off >>= 1) ls += __shfl_down(ls, off);
        if (lane == 0) lred[w] = ls;
    }
    __syncthreads();
    if (t == 0) {
        float bs = 0.f;
        #pragma unroll
        for (int i = 0; i < 8; ++i) bs += lred[i];
        atomicAdd(S, bs);
    }
}

__global__ void vq_final(const float* __restrict__ S, float* __restrict__ out) {
    float s = *S;
    out[LOSS_OFF] = 1.25f * s;
    out[COMMIT_OFF] = 0.25f * s;
    out[CODE_OFF] = s;
}

extern "C" void kernel_launch(void* const* d_in, const int* in_sizes, int n_in,
                              void* d_out, int out_size, void* d_ws, size_t ws_size,
                              hipStream_t stream) {
    const float* z = (const float*)d_in[0];
    const float* emb = (const float*)d_in[1];
    float* out = (float*)d_out;
    float* S = (float*)d_ws;
    unsigned char* img = (unsigned char*)d_ws + WS_IMG_OFF;   // needs ~336 KB of ws

    vq_prep<<<K, 64, 0, stream>>>(emb, img, S);
    vq_main<<<NBLK, 512, 0, stream>>>(z, emb, img, out, S);
    vq_final<<<1, 1, 0, stream>>>(S, out);
}